// Round 3
// baseline (2429.332 us; speedup 1.0000x reference)
//
#include <hip/hip_runtime.h>
#include <hip/hip_bf16.h>
#include <math.h>

typedef float  f4 __attribute__((ext_vector_type(4)));
typedef short  s8 __attribute__((ext_vector_type(8)));
typedef short  s4 __attribute__((ext_vector_type(4)));
typedef int    i2 __attribute__((ext_vector_type(2)));

#define NV 28
#define NB 32768
#define BN_EPS 1e-5f
#define NSLOT 434   // 28 col-sums + 406 upper-tri Gram products
#define XBLK 32     // xstats producer blocks (1024 rows each)

// ---- workspace layout (float indices unless noted) ----
#define SUM2_OFF   0        // 1792
#define SSQ2_OFF   1792     // 1792
#define BIAS1_OFF  3584     // 1792 -> 5376
#define GATE_OFF   5376     // 64 uints (spread); re-zeroed by k_prep EVERY run
#define PART_OFF   9472     // 32*434 floats
#define BF_BASE_F  120640   // bf16 region; byte 482560 (16B aligned)
#define W2B_OFF_S  57344    // short offset of W2 bf16
#define XBF_OFF_S  172032   // short offset of padded bf16 X [32768][32]
#define H2_BYTE_OFF 2924544ull
#define H2_BYTES    117440512ull      // 28*32768*64*2

#define SMEM_BYTES 34816    // pass1 arena is the max (5120+9216+18432+1024+1024)

// fast gelu via hw exp2/rcp; max abs err ~5e-4
__device__ __forceinline__ float gelu_f(float x) {
    float x2 = x * x;
    float z  = x * __builtin_fmaf(x2, -0.10294324f, -2.3022082f);
    float t  = __builtin_amdgcn_exp2f(z);
    return x * __builtin_amdgcn_rcpf(1.0f + t);
}
__device__ __forceinline__ unsigned short f2bf(float x) {
    unsigned u = __builtin_bit_cast(unsigned, x);
    return (unsigned short)((u + 0x7fffu + ((u >> 16) & 1u)) >> 16);
}
__device__ __forceinline__ int bfpack(float a, float b) {
    unsigned ua = __builtin_bit_cast(unsigned, a) + 0x8000u;
    unsigned ub = __builtin_bit_cast(unsigned, b) + 0x8000u;
    return __builtin_amdgcn_perm(ub, ua, 0x07060302);  // lo16=bf16(a), hi16=bf16(b)
}
__device__ __forceinline__ float row16_sum(float v) {
    int x;
    x = __builtin_amdgcn_update_dpp(0, __builtin_bit_cast(int, v), 0xB1, 0xF, 0xF, true);
    v += __builtin_bit_cast(float, x);
    x = __builtin_amdgcn_update_dpp(0, __builtin_bit_cast(int, v), 0x4E, 0xF, 0xF, true);
    v += __builtin_bit_cast(float, x);
    x = __builtin_amdgcn_update_dpp(0, __builtin_bit_cast(int, v), 0x124, 0xF, 0xF, true);
    v += __builtin_bit_cast(float, x);
    x = __builtin_amdgcn_update_dpp(0, __builtin_bit_cast(int, v), 0x128, 0xF, 0xF, true);
    v += __builtin_bit_cast(float, x);
    return v;
}
__device__ __forceinline__ float quad4_sum(float v) {
    int x;
    x = __builtin_amdgcn_update_dpp(0, __builtin_bit_cast(int, v), 0xB1, 0xF, 0xF, true);
    v += __builtin_bit_cast(float, x);
    x = __builtin_amdgcn_update_dpp(0, __builtin_bit_cast(int, v), 0x4E, 0xF, 0xF, true);
    v += __builtin_bit_cast(float, x);
    return v;
}

// ---- lightweight inter-block gates (NO grid.sync; no wholesale L2 flush) ----
// Producers: release-add. Consumers: relaxed spin + one acquire load.
// Gate cells are zeroed by k_prep each run (launch boundary = init visibility).
__device__ __forceinline__ void gate_signal(unsigned* c) {
    __syncthreads();   // all threads' prior stores drained (vmcnt) before release
    if (threadIdx.x == 0)
        __hip_atomic_fetch_add(c, 1u, __ATOMIC_RELEASE, __HIP_MEMORY_SCOPE_AGENT);
}
__device__ __forceinline__ void gate_wait(unsigned* c, unsigned tgt) {
    if (threadIdx.x == 0) {
        while (__hip_atomic_load(c, __ATOMIC_RELAXED, __HIP_MEMORY_SCOPE_AGENT) < tgt)
            __builtin_amdgcn_s_sleep(16);
        (void)__hip_atomic_load(c, __ATOMIC_ACQUIRE, __HIP_MEMORY_SCOPE_AGENT);
    }
    __syncthreads();
}

__device__ __forceinline__ void slot_de(int s, int& d, int& e) {
    int p = s - 28, dd = 0, rem = 28;
    while (p >= rem) { p -= rem; ++dd; --rem; }
    d = dd; e = dd + p;
}

// ------ k_prep: X stats partials (32 blocks x 1024 rows) + bf16 X + init block --
__global__ __launch_bounds__(256) void k_prep(const float* __restrict__ X,
                                              const float* __restrict__ Wlog,
                                              float* __restrict__ ws,
                                              float* __restrict__ out) {
    __shared__ float sx[128 * 28];
    const int b = blockIdx.x, tid = threadIdx.x;
    if (b == XBLK) {   // utility block: zero stats accumulators + gates; write adjacency W
        for (int i = tid; i < 3584; i += 256) ws[SUM2_OFF + i] = 0.0f;
        unsigned* gates = (unsigned*)(ws + GATE_OFF);
        if (tid < 64) gates[tid] = 0u;
        for (int i = tid; i < 784; i += 256) {
            float w = 1.0f / (1.0f + expf(-Wlog[i]));
            if ((i / 28) == (i % 28)) w = 0.0f;
            out[917504 + i] = w;
        }
        return;
    }
    // slot assignment: thread handles slots tid and tid+256
    const int s0 = tid, s1 = tid + 256;
    int d0 = 0, e0 = 0, d1 = 0, e1 = 0;
    if (s0 >= 28) slot_de(s0, d0, e0);
    slot_de(s1, d1, e1);               // s1 in [256,434) -> always Gram slot
    float a0 = 0.0f, a1 = 0.0f;
    int* xb = (int*)((short*)(ws + BF_BASE_F) + XBF_OFF_S);
    for (int ss = 0; ss < 8; ++ss) {
        const int rowbase = b * 1024 + ss * 128;
        __syncthreads();   // previous sub-slab's readers done
        {
            const f4* src = (const f4*)(X + (size_t)rowbase * 28);
            f4* dst = (f4*)sx;
            for (int i = tid; i < 896; i += 256) dst[i] = src[i];
        }
        __syncthreads();
        for (int j = tid; j < 2048; j += 256) {
            int row = j >> 4, cc = j & 15;
            float lo = (2 * cc     < 28) ? sx[row * 28 + 2 * cc]     : 0.0f;
            float hi = (2 * cc + 1 < 28) ? sx[row * 28 + 2 * cc + 1] : 0.0f;
            xb[(size_t)(rowbase + row) * 16 + cc] = (int)f2bf(lo) | ((int)f2bf(hi) << 16);
        }
        if (s0 < 28) {
            for (int r = 0; r < 128; ++r) a0 += sx[r * 28 + s0];
        } else {
            for (int r = 0; r < 128; ++r)
                a0 = __builtin_fmaf(sx[r * 28 + d0], sx[r * 28 + e0], a0);
        }
        if (s1 < NSLOT) {
            for (int r = 0; r < 128; ++r)
                a1 = __builtin_fmaf(sx[r * 28 + d1], sx[r * 28 + e1], a1);
        }
    }
    ws[PART_OFF + b * NSLOT + s0] = a0;
    if (s1 < NSLOT) ws[PART_OFF + b * NSLOT + s1] = a1;
}

// ------ fold phase: reduce partials; sigmoid mask; analytic BN1 -> bf16 weights --
__device__ __forceinline__ void fold_phase(char* smemc, const float* __restrict__ Wlog,
                                           const float* __restrict__ W1,
                                           const float* __restrict__ g1,
                                           const float* __restrict__ be1,
                                           const float* __restrict__ W2,
                                           float* __restrict__ ws, int n) {
    float* fb    = (float*)smemc;
    float* sstat = fb;            // 434
    float* mu    = fb + 434;      // 28
    float* wrow  = fb + 462;      // 28
    float* C     = fb + 490;      // 784
    float* w1e_s = fb + 1274;     // 1792 -> 12264 B total
    const int t = threadIdx.x;

    for (int s = t; s < NSLOT; s += 256) {
        float a = 0.0f;
#pragma unroll 8
        for (int p = 0; p < XBLK; ++p) a += ws[PART_OFF + p * NSLOT + s];
        sstat[s] = a;
    }
    __syncthreads();
    if (t < 28) {
        mu[t] = sstat[t] * (1.0f / 32768.0f);
        float w = 1.0f / (1.0f + expf(-Wlog[n * 28 + t]));
        if (t == n) w = 0.0f;
        wrow[t] = w;
    }
    __syncthreads();
    for (int i = t; i < 784; i += 256) {
        int d = i / 28, e = i % 28;
        int lo = d < e ? d : e, hi = d < e ? e : d;
        int idx = 28 + lo * 28 - (lo * (lo - 1)) / 2 + (hi - lo);
        C[i] = sstat[idx] * (1.0f / 32768.0f) - mu[d] * mu[e];
    }
    for (int i = t; i < 1792; i += 256)
        w1e_s[i] = W1[(size_t)n * 1792 + i] * wrow[i % 28];
    __syncthreads();

    const int h = t >> 2, j = t & 3;
    const float* we = &w1e_s[h * 28];
    float var_p = 0.0f, dot_p = 0.0f;
#pragma unroll
    for (int k = 0; k < 7; ++k) {
        int d = 7 * j + k;
        float inner = 0.0f;
#pragma unroll
        for (int e = 0; e < 28; ++e) inner = __builtin_fmaf(C[d * 28 + e], we[e], inner);
        float wd = we[d];
        var_p = __builtin_fmaf(inner, wd, var_p);
        dot_p = __builtin_fmaf(wd, mu[d], dot_p);
    }
    float var  = quad4_sum(var_p);
    float dotm = quad4_sum(dot_p);
    float scale = g1[n * 64 + h] * rsqrtf(fmaxf(var, 0.0f) + BN_EPS);
    if (j == 0)
        ws[BIAS1_OFF + n * 64 + h] = be1[n * 64 + h] - dotm * scale;

    short* bfbase = (short*)(ws + BF_BASE_F);
    {
        short* w1f = bfbase + (size_t)(n * 64 + h) * 32;
        s8 pk;
#pragma unroll
        for (int k = 0; k < 8; ++k) {
            int d = 8 * j + k;
            pk[k] = (short)f2bf(d < 28 ? we[d] * scale : 0.0f);
        }
        *(s8*)&w1f[8 * j] = pk;
    }
    {
        const float* w2src = W2 + (size_t)n * 4096 + t * 16;
        short* w2d = bfbase + W2B_OFF_S + (size_t)n * 4096 + t * 16;
        s8 a, b;
#pragma unroll
        for (int k = 0; k < 8; ++k) a[k] = (short)f2bf(w2src[k]);
#pragma unroll
        for (int k = 0; k < 8; ++k) b[k] = (short)f2bf(w2src[8 + k]);
        *(s8*)&w2d[0] = a;
        *(s8*)&w2d[8] = b;
    }
}

// ------ pass1 item (128 rows): GEMM1+gelu+GEMM2, reg stats, bf16 h2 store ------
// body = proven r10 k_pass1<true> config with the 2-iter loop unrolled to items.
__device__ __forceinline__ void pass1_item(char* smemc, float* __restrict__ ws,
                                           short* __restrict__ h2buf, int item) {
    short* sW1 = (short*)smemc;            // 5120 B
    short* sW2 = (short*)(smemc + 5120);   // 9216 B
    short* sA1 = (short*)(smemc + 14336);  // 18432 B
    float* sP1 = (float*)(smemc + 32768);  // 1024 B
    float* sP2 = (float*)(smemc + 33792);  // 1024 B
    const int n = item >> 8;
    const int blk = item & 255;
    const int tid = threadIdx.x;
    const int wave = tid >> 6;
    const int lane = tid & 63;
    const int m = lane & 15;
    const int q = lane >> 4;

    const short* bfbase = (const short*)(ws + BF_BASE_F);
    const short* w1g = bfbase + (size_t)n * 64 * 32;
    const short* w2g = bfbase + W2B_OFF_S + (size_t)n * 64 * 64;
    const short* xbf = bfbase + XBF_OFF_S;

    __syncthreads();   // arena safe to overwrite (previous item fully consumed)
    {
        int r = tid >> 2, c = tid & 3;
        *(s8*)&sW1[r * 40 + c * 8] = *(const s8*)&w1g[r * 32 + c * 8];
#pragma unroll
        for (int k = 0; k < 2; ++k) {
            int i2x = tid + k * 256;
            int r2 = i2x >> 3, c2 = i2x & 7;
            *(s8*)&sW2[r2 * 72 + c2 * 8] = *(const s8*)&w2g[r2 * 64 + c2 * 8];
        }
    }
    __syncthreads();

    const float* bias1 = ws + BIAS1_OFF + n * 64;
    f4 biasv[4];
#pragma unroll
    for (int t = 0; t < 4; ++t) biasv[t] = *(const f4*)&bias1[16 * t + 4 * q];

    short* myA1a = &sA1[(wave * 2 + 0) * 16 * 72];
    short* myA1b = &sA1[(wave * 2 + 1) * 16 * 72];
    float s1[16], s2v[16];
#pragma unroll
    for (int i = 0; i < 16; ++i) { s1[i] = 0.0f; s2v[i] = 0.0f; }

    const int row0 = blk * 128 + wave * 32;
    s8 xfa = *(const s8*)&xbf[(size_t)(row0 + m) * 32 + 8 * q];
    s8 xfb = *(const s8*)&xbf[(size_t)(row0 + 16 + m) * 32 + 8 * q];

    f4 acc1a[4], acc1b[4];
#pragma unroll
    for (int t = 0; t < 4; ++t) {
        s8 wf = *(const s8*)&sW1[(16 * t + m) * 40 + q * 8];
        acc1a[t] = __builtin_amdgcn_mfma_f32_16x16x32_bf16(wf, xfa, (f4){0.f, 0.f, 0.f, 0.f}, 0, 0, 0);
        acc1b[t] = __builtin_amdgcn_mfma_f32_16x16x32_bf16(wf, xfb, (f4){0.f, 0.f, 0.f, 0.f}, 0, 0, 0);
    }
#pragma unroll
    for (int t = 0; t < 4; ++t) {
        float ga0 = gelu_f(acc1a[t][0] + biasv[t][0]);
        float ga1 = gelu_f(acc1a[t][1] + biasv[t][1]);
        float ga2 = gelu_f(acc1a[t][2] + biasv[t][2]);
        float ga3 = gelu_f(acc1a[t][3] + biasv[t][3]);
        float gb0 = gelu_f(acc1b[t][0] + biasv[t][0]);
        float gb1 = gelu_f(acc1b[t][1] + biasv[t][1]);
        float gb2 = gelu_f(acc1b[t][2] + biasv[t][2]);
        float gb3 = gelu_f(acc1b[t][3] + biasv[t][3]);
        i2 pa = (i2){bfpack(ga0, ga1), bfpack(ga2, ga3)};
        i2 pb = (i2){bfpack(gb0, gb1), bfpack(gb2, gb3)};
        *(i2*)&myA1a[m * 72 + 16 * t + 4 * q] = pa;
        *(i2*)&myA1b[m * 72 + 16 * t + 4 * q] = pb;
    }
    // in-wave LDS ordering only; sA1 tiles are wave-private
    s8 af0a = *(const s8*)&myA1a[m * 72 + 8 * q];
    s8 af1a = *(const s8*)&myA1a[m * 72 + 32 + 8 * q];
    s8 af0b = *(const s8*)&myA1b[m * 72 + 8 * q];
    s8 af1b = *(const s8*)&myA1b[m * 72 + 32 + 8 * q];
    short* hpA = h2buf + ((size_t)n * NB + row0 + m) * 64;
    short* hpB = h2buf + ((size_t)n * NB + row0 + 16 + m) * 64;
#pragma unroll
    for (int u = 0; u < 4; ++u) {
        s8 w0 = *(const s8*)&sW2[(16 * u + m) * 72 + 8 * q];
        s8 w1 = *(const s8*)&sW2[(16 * u + m) * 72 + 32 + 8 * q];
        f4 aa = (f4){0.f, 0.f, 0.f, 0.f};
        f4 ab = (f4){0.f, 0.f, 0.f, 0.f};
        aa = __builtin_amdgcn_mfma_f32_16x16x32_bf16(w0, af0a, aa, 0, 0, 0);
        ab = __builtin_amdgcn_mfma_f32_16x16x32_bf16(w0, af0b, ab, 0, 0, 0);
        aa = __builtin_amdgcn_mfma_f32_16x16x32_bf16(w1, af1a, aa, 0, 0, 0);
        ab = __builtin_amdgcn_mfma_f32_16x16x32_bf16(w1, af1b, ab, 0, 0, 0);
        i2 ha = (i2){bfpack(aa[0], aa[1]), bfpack(aa[2], aa[3])};
        i2 hb = (i2){bfpack(ab[0], ab[1]), bfpack(ab[2], ab[3])};
        *(i2*)&hpA[16 * u + 4 * q] = ha;
        *(i2*)&hpB[16 * u + 4 * q] = hb;
#pragma unroll
        for (int r = 0; r < 4; ++r) {
            s1[u * 4 + r]  += aa[r] + ab[r];
            s2v[u * 4 + r] = __builtin_fmaf(aa[r], aa[r], s2v[u * 4 + r]);
            s2v[u * 4 + r] = __builtin_fmaf(ab[r], ab[r], s2v[u * 4 + r]);
        }
    }
#pragma unroll
    for (int u = 0; u < 4; ++u) {
#pragma unroll
        for (int r = 0; r < 4; ++r) {
            float t1 = row16_sum(s1[u * 4 + r]);
            float t2 = row16_sum(s2v[u * 4 + r]);
            if (m == 0) {
                sP1[wave * 64 + 16 * u + 4 * q + r] = t1;
                sP2[wave * 64 + 16 * u + 4 * q + r] = t2;
            }
        }
    }
    __syncthreads();
    if (tid < 64) {
        float a = sP1[tid] + sP1[64 + tid] + sP1[128 + tid] + sP1[192 + tid];
        float b = sP2[tid] + sP2[64 + tid] + sP2[128 + tid] + sP2[192 + tid];
        atomicAdd(&ws[SUM2_OFF + n * 64 + tid], a);
        atomicAdd(&ws[SSQ2_OFF + n * 64 + tid], b);
    }
}

// ------ pass2 item (128 rows, stored h2, coalesced): BN2+gelu+GEMM3 -> X_hat ---
__device__ __forceinline__ void pass2_item(char* smemc, const float* __restrict__ g2,
                                           const float* __restrict__ be2,
                                           const float* __restrict__ W3,
                                           const float* __restrict__ b3,
                                           const float* __restrict__ ws,
                                           const short* __restrict__ h2buf,
                                           float* __restrict__ out, int item) {
    float* sSc  = (float*)smemc;
    float* sSh  = (float*)smemc + 64;
    float* sW3v = (float*)smemc + 128;
    const int n = item >> 8;
    const int rbase = (item & 255) * 128;
    const int tid = threadIdx.x;
    __syncthreads();   // arena reuse guard
    if (tid < 64) {
        float mean = ws[SUM2_OFF + n * 64 + tid] * (1.0f / 32768.0f);
        float var  = ws[SSQ2_OFF + n * 64 + tid] * (1.0f / 32768.0f) - mean * mean;
        float sc = g2[n * 64 + tid] * rsqrtf(fmaxf(var, 0.0f) + BN_EPS);
        sSc[tid]  = sc;
        sSh[tid]  = be2[n * 64 + tid] - mean * sc;
        sW3v[tid] = W3[n * 64 + tid];
    }
    __syncthreads();
    const int wave = tid >> 6;
    const int lane = tid & 63;
    const int rr = lane >> 3;
    const int cc = lane & 7;
    f4 scA = *(const f4*)&sSc[cc * 8],  scB = *(const f4*)&sSc[cc * 8 + 4];
    f4 shA = *(const f4*)&sSh[cc * 8],  shB = *(const f4*)&sSh[cc * 8 + 4];
    f4 w3A = *(const f4*)&sW3v[cc * 8], w3B = *(const f4*)&sW3v[cc * 8 + 4];
    const float b3n = b3[n];
#pragma unroll
    for (int it = 0; it < 4; ++it) {
        const int row = rbase + wave * 32 + it * 8 + rr;
        s8 hv = *(const s8*)(h2buf + ((size_t)n * NB + row) * 64 + cc * 8);
        float p = 0.0f;
#pragma unroll
        for (int j = 0; j < 4; ++j) {
            float v = __builtin_fmaf(__builtin_bit_cast(float, ((int)(unsigned short)hv[j]) << 16), scA[j], shA[j]);
            p = __builtin_fmaf(gelu_f(v), w3A[j], p);
        }
#pragma unroll
        for (int j = 0; j < 4; ++j) {
            float v = __builtin_fmaf(__builtin_bit_cast(float, ((int)(unsigned short)hv[4 + j]) << 16), scB[j], shB[j]);
            p = __builtin_fmaf(gelu_f(v), w3B[j], p);
        }
        p += __shfl_xor(p, 1);
        p += __shfl_xor(p, 2);
        p += __shfl_xor(p, 4);
        if (cc == 0) out[(size_t)row * 28 + n] = p + b3n;
    }
}

// ---------- gated main kernel: fold -> pass1 -> pass2 in ONE launch ----------
// Cooperative launch is used ONLY for the co-residency guarantee (spin gates
// are deadlock-free iff all blocks resident). NO grid.sync() anywhere — R2
// measured it at ~125 us/sync (L2 flush + sleep-backoff barrier).
__global__ __launch_bounds__(256, 4) void k_mainG(const float* __restrict__ Wlog,
                                                  const float* __restrict__ W1,
                                                  const float* __restrict__ g1,
                                                  const float* __restrict__ be1,
                                                  const float* __restrict__ W2,
                                                  const float* __restrict__ g2,
                                                  const float* __restrict__ be2,
                                                  const float* __restrict__ W3,
                                                  const float* __restrict__ b3,
                                                  float* __restrict__ ws,
                                                  short* __restrict__ h2buf,
                                                  float* __restrict__ out) {
    __shared__ __align__(16) char smem[SMEM_BYTES];
    unsigned* gates = (unsigned*)(ws + GATE_OFF);
    const int b = blockIdx.x;
    const int G = gridDim.x;

    if (b < 28) {
        fold_phase(smem, Wlog, W1, g1, be1, W2, ws, b);
        gate_signal(&gates[0]);
    }
    gate_wait(&gates[0], 28u);

    for (int item = b; item < 7168; item += G)
        pass1_item(smem, ws, h2buf, item);
    gate_signal(&gates[8]);
    gate_wait(&gates[8], (unsigned)G);

    for (int item = b; item < 7168; item += G)
        pass2_item(smem, g2, be2, W3, b3, ws, h2buf, out, item);
}

// ---------- fallback thin kernels (no gates; plain launch boundaries) ----------
__global__ __launch_bounds__(256) void kf_fold(const float* __restrict__ Wlog,
                                               const float* __restrict__ W1,
                                               const float* __restrict__ g1,
                                               const float* __restrict__ be1,
                                               const float* __restrict__ W2,
                                               float* __restrict__ ws) {
    __shared__ __align__(16) char smem[SMEM_BYTES];
    fold_phase(smem, Wlog, W1, g1, be1, W2, ws, blockIdx.x);
}
__global__ __launch_bounds__(256, 4) void kf_p1(float* __restrict__ ws,
                                                short* __restrict__ h2buf) {
    __shared__ __align__(16) char smem[SMEM_BYTES];
    pass1_item(smem, ws, h2buf, blockIdx.x);
}
__global__ __launch_bounds__(256, 4) void kf_p2(const float* __restrict__ g2,
                                                const float* __restrict__ be2,
                                                const float* __restrict__ W3,
                                                const float* __restrict__ b3,
                                                const float* __restrict__ ws,
                                                const short* __restrict__ h2buf,
                                                float* __restrict__ out) {
    __shared__ __align__(16) char smem[SMEM_BYTES];
    pass2_item(smem, g2, be2, W3, b3, ws, h2buf, out, blockIdx.x);
}

extern "C" void kernel_launch(void* const* d_in, const int* in_sizes, int n_in,
                              void* d_out, int out_size, void* d_ws, size_t ws_size,
                              hipStream_t stream) {
    const float* X   = (const float*)d_in[0];
    const float* Wl  = (const float*)d_in[1];
    const float* W1  = (const float*)d_in[2];
    const float* g1  = (const float*)d_in[4];
    const float* be1 = (const float*)d_in[5];
    const float* W2  = (const float*)d_in[6];
    const float* g2  = (const float*)d_in[8];
    const float* be2 = (const float*)d_in[9];
    const float* W3  = (const float*)d_in[10];
    const float* b3  = (const float*)d_in[11];
    float* out = (float*)d_out;
    float* ws  = (float*)d_ws;
    short* h2buf = (short*)((char*)d_ws + H2_BYTE_OFF);

    // one-time host-side capability probe (pure queries; graph-capture safe — same
    // pattern ran fine in R2)
    static int gmain = 0;   // 0 = uninit, -1 = fallback, >0 = cooperative grid size
    if (gmain == 0) {
        int dev = 0;
        hipDeviceProp_t prop;
        bool ok = (hipGetDevice(&dev) == hipSuccess) &&
                  (hipGetDeviceProperties(&prop, dev) == hipSuccess) &&
                  prop.cooperativeLaunch;
        int bpc = 0;
        if (ok &&
            hipOccupancyMaxActiveBlocksPerMultiprocessor(&bpc, k_mainG, 256, 0) == hipSuccess &&
            bpc > 0) {
            long g = (long)bpc * prop.multiProcessorCount;
            if (g > 1024) g = 1024;   // 7168 = 7*1024: balanced item partition
            gmain = (g >= 64) ? (int)g : -1;
        } else {
            gmain = -1;
        }
    }

    k_prep<<<dim3(XBLK + 1), dim3(256), 0, stream>>>(X, Wl, ws, out);

    bool done = false;
    if (gmain > 0) {
        void* args[12] = {(void*)&Wl, (void*)&W1, (void*)&g1, (void*)&be1, (void*)&W2,
                          (void*)&g2, (void*)&be2, (void*)&W3, (void*)&b3,
                          (void*)&ws, (void*)&h2buf, (void*)&out};
        hipError_t e = hipLaunchCooperativeKernel(reinterpret_cast<const void*>(k_mainG),
                                                  dim3(gmain), dim3(256), args, 0, stream);
        if (e == hipSuccess) done = true;
        else gmain = -1;
    }
    if (!done) {
        kf_fold<<<dim3(28),   dim3(256), 0, stream>>>(Wl, W1, g1, be1, W2, ws);
        kf_p1  <<<dim3(7168), dim3(256), 0, stream>>>(ws, h2buf);
        kf_p2  <<<dim3(7168), dim3(256), 0, stream>>>(g2, be2, W3, b3, ws, h2buf, out);
    }
}

// Round 4
// 177.794 us; speedup vs baseline: 13.6637x; 13.6637x over previous
//
#include <hip/hip_runtime.h>
#include <hip/hip_bf16.h>
#include <math.h>

typedef float  f4 __attribute__((ext_vector_type(4)));
typedef short  s8 __attribute__((ext_vector_type(8)));
typedef short  s4 __attribute__((ext_vector_type(4)));
typedef int    i2 __attribute__((ext_vector_type(2)));

#define NV 28
#define NB 32768
#define BN_EPS 1e-5f
#define NSLOT 434   // 28 col-sums + 406 upper-tri Gram products

// ---- workspace layout (float indices unless noted) ----
#define SUM2_OFF   0        // 1792
#define SSQ2_OFF   1792     // 1792
#define BIAS1_OFF  3584     // 1792 -> 5376
#define GATE_OFF   5376     // 28 counters, 32-uint (128 B) spacing; zeroed every run
#define PART_OFF   9472     // 256*434 -> 120576
#define BF_BASE_F  120640   // bf16 region; byte 482560 (16B aligned)
#define W2B_OFF_S  57344    // short offset of W2 bf16
#define XBF_OFF_S  172032   // short offset of padded bf16 X [32768][32]
#define H2_BYTE_OFF 2924544ull
#define H2_BYTES    117440512ull      // 28*32768*64*2

#define SMEM_BYTES 34816    // pass1 arena (5120+9216+18432+1024+1024)
#define GMAIN 896           // 28 mech * 32 chunks-of-4: 3584 items / 896 = 4 items/block

// fast gelu via hw exp2/rcp; max abs err ~5e-4
__device__ __forceinline__ float gelu_f(float x) {
    float x2 = x * x;
    float z  = x * __builtin_fmaf(x2, -0.10294324f, -2.3022082f);
    float t  = __builtin_amdgcn_exp2f(z);
    return x * __builtin_amdgcn_rcpf(1.0f + t);
}
__device__ __forceinline__ unsigned short f2bf(float x) {
    unsigned u = __builtin_bit_cast(unsigned, x);
    return (unsigned short)((u + 0x7fffu + ((u >> 16) & 1u)) >> 16);
}
__device__ __forceinline__ int bfpack(float a, float b) {
    unsigned ua = __builtin_bit_cast(unsigned, a) + 0x8000u;
    unsigned ub = __builtin_bit_cast(unsigned, b) + 0x8000u;
    return __builtin_amdgcn_perm(ub, ua, 0x07060302);  // lo16=bf16(a), hi16=bf16(b)
}
__device__ __forceinline__ float row16_sum(float v) {
    int x;
    x = __builtin_amdgcn_update_dpp(0, __builtin_bit_cast(int, v), 0xB1, 0xF, 0xF, true);
    v += __builtin_bit_cast(float, x);
    x = __builtin_amdgcn_update_dpp(0, __builtin_bit_cast(int, v), 0x4E, 0xF, 0xF, true);
    v += __builtin_bit_cast(float, x);
    x = __builtin_amdgcn_update_dpp(0, __builtin_bit_cast(int, v), 0x124, 0xF, 0xF, true);
    v += __builtin_bit_cast(float, x);
    x = __builtin_amdgcn_update_dpp(0, __builtin_bit_cast(int, v), 0x128, 0xF, 0xF, true);
    v += __builtin_bit_cast(float, x);
    return v;
}
__device__ __forceinline__ float quad4_sum(float v) {
    int x;
    x = __builtin_amdgcn_update_dpp(0, __builtin_bit_cast(int, v), 0xB1, 0xF, 0xF, true);
    v += __builtin_bit_cast(float, x);
    x = __builtin_amdgcn_update_dpp(0, __builtin_bit_cast(int, v), 0x4E, 0xF, 0xF, true);
    v += __builtin_bit_cast(float, x);
    return v;
}

// ------ k_prep: proven 128-row-slab xstats (256 blocks) + util block -----------
__global__ __launch_bounds__(256) void k_prep(const float* __restrict__ X,
                                              const float* __restrict__ Wlog,
                                              float* __restrict__ ws,
                                              float* __restrict__ out) {
    __shared__ float sx[128 * 28];
    const int b = blockIdx.x, tid = threadIdx.x;
    if (b == 256) {   // utility block: zero stats + gates; write adjacency W
        for (int i = tid; i < 3584; i += 256) ws[SUM2_OFF + i] = 0.0f;
        unsigned* gates = (unsigned*)(ws + GATE_OFF);
        for (int i = tid; i < 28 * 32; i += 256) gates[i] = 0u;
        for (int i = tid; i < 784; i += 256) {
            float w = 1.0f / (1.0f + expf(-Wlog[i]));
            if ((i / 28) == (i % 28)) w = 0.0f;
            out[917504 + i] = w;
        }
        return;
    }
    const int rowbase = b * 128;
    {
        const f4* src = (const f4*)(X + (size_t)rowbase * 28);
        f4* dst = (f4*)sx;
        for (int i = tid; i < 128 * 28 / 4; i += 256) dst[i] = src[i];
    }
    __syncthreads();
    // bf16 X, padded to 32 cols (cols 28..31 zero)
    int* xb = (int*)((short*)(ws + BF_BASE_F) + XBF_OFF_S);
    for (int j = tid; j < 128 * 16; j += 256) {
        int row = j >> 4, cc = j & 15;
        float lo = (2 * cc     < 28) ? sx[row * 28 + 2 * cc]     : 0.0f;
        float hi = (2 * cc + 1 < 28) ? sx[row * 28 + 2 * cc + 1] : 0.0f;
        xb[(size_t)(rowbase + row) * 16 + cc] = (int)f2bf(lo) | ((int)f2bf(hi) << 16);
    }
    // slots: 0..27 col sums, 28.. upper-tri products (d<=e); decode only for s<NSLOT
    for (int s = tid; s < NSLOT; s += 256) {
        float a = 0.0f;
        if (s < 28) {
            for (int r = 0; r < 128; ++r) a += sx[r * 28 + s];
        } else {
            int p = s - 28, d = 0, rem = 28;
            while (p >= rem) { p -= rem; ++d; --rem; }
            int e = d + p;
            for (int r = 0; r < 128; ++r)
                a = __builtin_fmaf(sx[r * 28 + d], sx[r * 28 + e], a);
        }
        ws[PART_OFF + b * NSLOT + s] = a;
    }
}

// ------ k_fold: own launch (weight visibility via launch boundary; no gates) ---
__global__ __launch_bounds__(256) void k_fold(const float* __restrict__ Wlog,
                                              const float* __restrict__ W1,
                                              const float* __restrict__ g1,
                                              const float* __restrict__ be1,
                                              const float* __restrict__ W2,
                                              float* __restrict__ ws) {
    __shared__ float sstat[NSLOT];
    __shared__ float mu[28], wrow[28];
    __shared__ float C[784];
    __shared__ float w1e_s[64 * 28];
    const int n = blockIdx.x, t = threadIdx.x;

    for (int s = t; s < NSLOT; s += 256) {
        float a = 0.0f;
#pragma unroll 16
        for (int p = 0; p < 256; ++p) a += ws[PART_OFF + p * NSLOT + s];
        sstat[s] = a;
    }
    __syncthreads();
    if (t < 28) {
        mu[t] = sstat[t] * (1.0f / 32768.0f);
        float w = 1.0f / (1.0f + expf(-Wlog[n * 28 + t]));
        if (t == n) w = 0.0f;
        wrow[t] = w;
    }
    __syncthreads();
    for (int i = t; i < 784; i += 256) {
        int d = i / 28, e = i % 28;
        int lo = d < e ? d : e, hi = d < e ? e : d;
        int idx = 28 + lo * 28 - (lo * (lo - 1)) / 2 + (hi - lo);
        C[i] = sstat[idx] * (1.0f / 32768.0f) - mu[d] * mu[e];
    }
    for (int i = t; i < 1792; i += 256)
        w1e_s[i] = W1[(size_t)n * 1792 + i] * wrow[i % 28];
    __syncthreads();

    const int h = t >> 2, j = t & 3;
    const float* we = &w1e_s[h * 28];
    float var_p = 0.0f, dot_p = 0.0f;
#pragma unroll
    for (int k = 0; k < 7; ++k) {
        int d = 7 * j + k;
        float inner = 0.0f;
#pragma unroll
        for (int e = 0; e < 28; ++e) inner = __builtin_fmaf(C[d * 28 + e], we[e], inner);
        float wd = we[d];
        var_p = __builtin_fmaf(inner, wd, var_p);
        dot_p = __builtin_fmaf(wd, mu[d], dot_p);
    }
    float var  = quad4_sum(var_p);
    float dotm = quad4_sum(dot_p);
    float scale = g1[n * 64 + h] * rsqrtf(fmaxf(var, 0.0f) + BN_EPS);
    if (j == 0)
        ws[BIAS1_OFF + n * 64 + h] = be1[n * 64 + h] - dotm * scale;

    short* bfbase = (short*)(ws + BF_BASE_F);
    {
        short* w1f = bfbase + (size_t)(n * 64 + h) * 32;
        s8 pk;
#pragma unroll
        for (int k = 0; k < 8; ++k) {
            int d = 8 * j + k;
            pk[k] = (short)f2bf(d < 28 ? we[d] * scale : 0.0f);
        }
        *(s8*)&w1f[8 * j] = pk;
    }
    {
        const float* w2src = W2 + (size_t)n * 4096 + t * 16;
        short* w2d = bfbase + W2B_OFF_S + (size_t)n * 4096 + t * 16;
        s8 a, b;
#pragma unroll
        for (int k = 0; k < 8; ++k) a[k] = (short)f2bf(w2src[k]);
#pragma unroll
        for (int k = 0; k < 8; ++k) b[k] = (short)f2bf(w2src[8 + k]);
        *(s8*)&w2d[0] = a;
        *(s8*)&w2d[8] = b;
    }
}

// ------ pass1 item (256 rows, exact r10 body): GEMM1+gelu+GEMM2 + h2 + stats ---
__device__ __forceinline__ void pass1_item(char* smemc, float* __restrict__ ws,
                                           short* __restrict__ h2buf, int item) {
    short* sW1 = (short*)smemc;            // 5120 B
    short* sW2 = (short*)(smemc + 5120);   // 9216 B
    short* sA1 = (short*)(smemc + 14336);  // 18432 B
    float* sP1 = (float*)(smemc + 32768);  // 1024 B
    float* sP2 = (float*)(smemc + 33792);  // 1024 B
    const int n = item >> 7;
    const int blk = item & 127;
    const int tid = threadIdx.x;
    const int wave = tid >> 6;
    const int lane = tid & 63;
    const int m = lane & 15;
    const int q = lane >> 4;

    const short* bfbase = (const short*)(ws + BF_BASE_F);
    const short* w1g = bfbase + (size_t)n * 64 * 32;
    const short* w2g = bfbase + W2B_OFF_S + (size_t)n * 64 * 64;
    const short* xbf = bfbase + XBF_OFF_S;

    __syncthreads();   // arena safe to overwrite (previous item fully consumed)
    {
        int r = tid >> 2, c = tid & 3;
        *(s8*)&sW1[r * 40 + c * 8] = *(const s8*)&w1g[r * 32 + c * 8];
#pragma unroll
        for (int k = 0; k < 2; ++k) {
            int i2x = tid + k * 256;
            int r2 = i2x >> 3, c2 = i2x & 7;
            *(s8*)&sW2[r2 * 72 + c2 * 8] = *(const s8*)&w2g[r2 * 64 + c2 * 8];
        }
    }
    __syncthreads();

    const float* bias1 = ws + BIAS1_OFF + n * 64;
    f4 biasv[4];
#pragma unroll
    for (int t = 0; t < 4; ++t) biasv[t] = *(const f4*)&bias1[16 * t + 4 * q];

    short* myA1a = &sA1[(wave * 2 + 0) * 16 * 72];
    short* myA1b = &sA1[(wave * 2 + 1) * 16 * 72];
    float s1[16], s2v[16];
#pragma unroll
    for (int i = 0; i < 16; ++i) { s1[i] = 0.0f; s2v[i] = 0.0f; }

#pragma unroll
    for (int it = 0; it < 2; ++it) {
        const int row0 = blk * 256 + it * 128 + wave * 32;
        s8 xfa = *(const s8*)&xbf[(size_t)(row0 + m) * 32 + 8 * q];
        s8 xfb = *(const s8*)&xbf[(size_t)(row0 + 16 + m) * 32 + 8 * q];

        f4 acc1a[4], acc1b[4];
#pragma unroll
        for (int t = 0; t < 4; ++t) {
            s8 wf = *(const s8*)&sW1[(16 * t + m) * 40 + q * 8];
            acc1a[t] = __builtin_amdgcn_mfma_f32_16x16x32_bf16(wf, xfa, (f4){0.f, 0.f, 0.f, 0.f}, 0, 0, 0);
            acc1b[t] = __builtin_amdgcn_mfma_f32_16x16x32_bf16(wf, xfb, (f4){0.f, 0.f, 0.f, 0.f}, 0, 0, 0);
        }
#pragma unroll
        for (int t = 0; t < 4; ++t) {
            float ga0 = gelu_f(acc1a[t][0] + biasv[t][0]);
            float ga1 = gelu_f(acc1a[t][1] + biasv[t][1]);
            float ga2 = gelu_f(acc1a[t][2] + biasv[t][2]);
            float ga3 = gelu_f(acc1a[t][3] + biasv[t][3]);
            float gb0 = gelu_f(acc1b[t][0] + biasv[t][0]);
            float gb1 = gelu_f(acc1b[t][1] + biasv[t][1]);
            float gb2 = gelu_f(acc1b[t][2] + biasv[t][2]);
            float gb3 = gelu_f(acc1b[t][3] + biasv[t][3]);
            i2 pa = (i2){bfpack(ga0, ga1), bfpack(ga2, ga3)};
            i2 pb = (i2){bfpack(gb0, gb1), bfpack(gb2, gb3)};
            *(i2*)&myA1a[m * 72 + 16 * t + 4 * q] = pa;
            *(i2*)&myA1b[m * 72 + 16 * t + 4 * q] = pb;
        }
        // in-wave LDS ordering only; sA1 tiles are wave-private
        s8 af0a = *(const s8*)&myA1a[m * 72 + 8 * q];
        s8 af1a = *(const s8*)&myA1a[m * 72 + 32 + 8 * q];
        s8 af0b = *(const s8*)&myA1b[m * 72 + 8 * q];
        s8 af1b = *(const s8*)&myA1b[m * 72 + 32 + 8 * q];
        short* hpA = h2buf + ((size_t)n * NB + row0 + m) * 64;
        short* hpB = h2buf + ((size_t)n * NB + row0 + 16 + m) * 64;
#pragma unroll
        for (int u = 0; u < 4; ++u) {
            s8 w0 = *(const s8*)&sW2[(16 * u + m) * 72 + 8 * q];
            s8 w1 = *(const s8*)&sW2[(16 * u + m) * 72 + 32 + 8 * q];
            f4 aa = (f4){0.f, 0.f, 0.f, 0.f};
            f4 ab = (f4){0.f, 0.f, 0.f, 0.f};
            aa = __builtin_amdgcn_mfma_f32_16x16x32_bf16(w0, af0a, aa, 0, 0, 0);
            ab = __builtin_amdgcn_mfma_f32_16x16x32_bf16(w0, af0b, ab, 0, 0, 0);
            aa = __builtin_amdgcn_mfma_f32_16x16x32_bf16(w1, af1a, aa, 0, 0, 0);
            ab = __builtin_amdgcn_mfma_f32_16x16x32_bf16(w1, af1b, ab, 0, 0, 0);
            i2 ha = (i2){bfpack(aa[0], aa[1]), bfpack(aa[2], aa[3])};
            i2 hb = (i2){bfpack(ab[0], ab[1]), bfpack(ab[2], ab[3])};
            *(i2*)&hpA[16 * u + 4 * q] = ha;
            *(i2*)&hpB[16 * u + 4 * q] = hb;
#pragma unroll
            for (int r = 0; r < 4; ++r) {
                s1[u * 4 + r]  += aa[r] + ab[r];
                s2v[u * 4 + r] = __builtin_fmaf(aa[r], aa[r], s2v[u * 4 + r]);
                s2v[u * 4 + r] = __builtin_fmaf(ab[r], ab[r], s2v[u * 4 + r]);
            }
        }
    }
#pragma unroll
    for (int u = 0; u < 4; ++u) {
#pragma unroll
        for (int r = 0; r < 4; ++r) {
            float t1 = row16_sum(s1[u * 4 + r]);
            float t2 = row16_sum(s2v[u * 4 + r]);
            if (m == 0) {
                sP1[wave * 64 + 16 * u + 4 * q + r] = t1;
                sP2[wave * 64 + 16 * u + 4 * q + r] = t2;
            }
        }
    }
    __syncthreads();
    if (tid < 64) {
        float a = sP1[tid] + sP1[64 + tid] + sP1[128 + tid] + sP1[192 + tid];
        float b = sP2[tid] + sP2[64 + tid] + sP2[128 + tid] + sP2[192 + tid];
        atomicAdd(&ws[SUM2_OFF + n * 64 + tid], a);
        atomicAdd(&ws[SSQ2_OFF + n * 64 + tid], b);
    }
}

// ------ pass2 item (256 rows, same block's own h2): BN2+gelu+GEMM3 -> X_hat ----
template <bool GATED>
__device__ __forceinline__ void pass2_item(char* smemc, const float* __restrict__ g2,
                                           const float* __restrict__ be2,
                                           const float* __restrict__ W3,
                                           const float* __restrict__ b3,
                                           float* __restrict__ ws,
                                           const short* __restrict__ h2buf,
                                           float* __restrict__ out, int item,
                                           unsigned* gates) {
    float* sSc  = (float*)smemc;
    float* sSh  = (float*)smemc + 64;
    float* sW3v = (float*)smemc + 128;
    const int n = item >> 7;
    const int rbase = (item & 127) * 256;
    const int tid = threadIdx.x;
    if (GATED && tid == 0) {   // relaxed spin; producers' adds completed pre-signal
        while (__hip_atomic_load(&gates[n * 32], __ATOMIC_RELAXED, __HIP_MEMORY_SCOPE_AGENT) < 128u)
            __builtin_amdgcn_s_sleep(2);
    }
    __syncthreads();   // spin release + arena reuse guard
    if (tid < 64) {
        float su, sq;
        if (GATED) {   // device-scope loads: read coherence point (no L2 inv needed)
            su = __hip_atomic_load(&ws[SUM2_OFF + n * 64 + tid], __ATOMIC_RELAXED, __HIP_MEMORY_SCOPE_AGENT);
            sq = __hip_atomic_load(&ws[SSQ2_OFF + n * 64 + tid], __ATOMIC_RELAXED, __HIP_MEMORY_SCOPE_AGENT);
        } else {
            su = ws[SUM2_OFF + n * 64 + tid];
            sq = ws[SSQ2_OFF + n * 64 + tid];
        }
        float mean = su * (1.0f / 32768.0f);
        float var  = sq * (1.0f / 32768.0f) - mean * mean;
        float sc = g2[n * 64 + tid] * rsqrtf(fmaxf(var, 0.0f) + BN_EPS);
        sSc[tid]  = sc;
        sSh[tid]  = be2[n * 64 + tid] - mean * sc;
        sW3v[tid] = W3[n * 64 + tid];
    }
    __syncthreads();
    const int wave = tid >> 6;
    const int lane = tid & 63;
    const int rr = lane >> 3;
    const int cc = lane & 7;
    f4 scA = *(const f4*)&sSc[cc * 8],  scB = *(const f4*)&sSc[cc * 8 + 4];
    f4 shA = *(const f4*)&sSh[cc * 8],  shB = *(const f4*)&sSh[cc * 8 + 4];
    f4 w3A = *(const f4*)&sW3v[cc * 8], w3B = *(const f4*)&sW3v[cc * 8 + 4];
    const float b3n = b3[n];
#pragma unroll
    for (int it = 0; it < 8; ++it) {
        const int row = rbase + wave * 64 + it * 8 + rr;
        s8 hv = *(const s8*)(h2buf + ((size_t)n * NB + row) * 64 + cc * 8);
        float p = 0.0f;
#pragma unroll
        for (int j = 0; j < 4; ++j) {
            float v = __builtin_fmaf(__builtin_bit_cast(float, ((int)(unsigned short)hv[j]) << 16), scA[j], shA[j]);
            p = __builtin_fmaf(gelu_f(v), w3A[j], p);
        }
#pragma unroll
        for (int j = 0; j < 4; ++j) {
            float v = __builtin_fmaf(__builtin_bit_cast(float, ((int)(unsigned short)hv[4 + j]) << 16), scB[j], shB[j]);
            p = __builtin_fmaf(gelu_f(v), w3B[j], p);
        }
        p += __shfl_xor(p, 1);
        p += __shfl_xor(p, 2);
        p += __shfl_xor(p, 4);
        if (cc == 0) out[(size_t)row * 28 + n] = p + b3n;
    }
}

// ---------- main kernel: pass1 (4 items) -> per-mech relaxed gates -> pass2 ----
// No release/acquire anywhere (no wbl2/inv storms). h2 is block-local: each
// block's pass2 reads exactly the rows its own pass1 wrote. Deadlock-free under
// cooperative co-residency: waits only happen after all pass1 items complete.
__global__ __launch_bounds__(256, 4) void k_mainG(const float* __restrict__ g2,
                                                  const float* __restrict__ be2,
                                                  const float* __restrict__ W3,
                                                  const float* __restrict__ b3,
                                                  float* __restrict__ ws,
                                                  short* __restrict__ h2buf,
                                                  float* __restrict__ out) {
    __shared__ __align__(16) char smem[SMEM_BYTES];
    unsigned* gates = (unsigned*)(ws + GATE_OFF);
    const int b = blockIdx.x;
    const int tid = threadIdx.x;

#pragma unroll 1
    for (int k = 0; k < 4; ++k) {
        const int item = b + k * GMAIN;
        pass1_item(smem, ws, h2buf, item);
        __syncthreads();   // drains vmcnt -> stat atomics complete before signal
        if (tid == 0)
            __hip_atomic_fetch_add(&gates[(item >> 7) * 32], 1u,
                                   __ATOMIC_RELAXED, __HIP_MEMORY_SCOPE_AGENT);
    }
#pragma unroll 1
    for (int k = 0; k < 4; ++k)
        pass2_item<true>(smem, g2, be2, W3, b3, ws, h2buf, out, b + k * GMAIN, gates);
}

// ---------- fallback thin kernels (plain launch boundaries, no gates) ----------
__global__ __launch_bounds__(256, 4) void kf_p1(float* __restrict__ ws,
                                                short* __restrict__ h2buf) {
    __shared__ __align__(16) char smem[SMEM_BYTES];
    pass1_item(smem, ws, h2buf, blockIdx.x);
}
__global__ __launch_bounds__(256, 4) void kf_p2(const float* __restrict__ g2,
                                                const float* __restrict__ be2,
                                                const float* __restrict__ W3,
                                                const float* __restrict__ b3,
                                                float* __restrict__ ws,
                                                const short* __restrict__ h2buf,
                                                float* __restrict__ out) {
    __shared__ __align__(16) char smem[SMEM_BYTES];
    pass2_item<false>(smem, g2, be2, W3, b3, ws, h2buf, out, blockIdx.x, nullptr);
}

extern "C" void kernel_launch(void* const* d_in, const int* in_sizes, int n_in,
                              void* d_out, int out_size, void* d_ws, size_t ws_size,
                              hipStream_t stream) {
    const float* X   = (const float*)d_in[0];
    const float* Wl  = (const float*)d_in[1];
    const float* W1  = (const float*)d_in[2];
    const float* g1  = (const float*)d_in[4];
    const float* be1 = (const float*)d_in[5];
    const float* W2  = (const float*)d_in[6];
    const float* g2  = (const float*)d_in[8];
    const float* be2 = (const float*)d_in[9];
    const float* W3  = (const float*)d_in[10];
    const float* b3  = (const float*)d_in[11];
    float* out = (float*)d_out;
    float* ws  = (float*)d_ws;
    short* h2buf = (short*)((char*)d_ws + H2_BYTE_OFF);

    // one-time host-side capability probe (pure queries; graph-capture safe)
    static int gmain = 0;   // 0 = uninit, -1 = fallback, 1 = cooperative ok
    if (gmain == 0) {
        int dev = 0;
        hipDeviceProp_t prop;
        bool ok = (hipGetDevice(&dev) == hipSuccess) &&
                  (hipGetDeviceProperties(&prop, dev) == hipSuccess) &&
                  prop.cooperativeLaunch;
        int bpc = 0;
        if (ok &&
            hipOccupancyMaxActiveBlocksPerMultiprocessor(&bpc, k_mainG, 256, 0) == hipSuccess &&
            (long)bpc * prop.multiProcessorCount >= GMAIN) {
            gmain = 1;
        } else {
            gmain = -1;
        }
    }

    k_prep<<<dim3(257), dim3(256), 0, stream>>>(X, Wl, ws, out);
    k_fold<<<dim3(28),  dim3(256), 0, stream>>>(Wl, W1, g1, be1, W2, ws);

    bool done = false;
    if (gmain > 0) {
        void* args[7] = {(void*)&g2, (void*)&be2, (void*)&W3, (void*)&b3,
                         (void*)&ws, (void*)&h2buf, (void*)&out};
        hipError_t e = hipLaunchCooperativeKernel(reinterpret_cast<const void*>(k_mainG),
                                                  dim3(GMAIN), dim3(256), args, 0, stream);
        if (e == hipSuccess) done = true;
        else gmain = -1;
    }
    if (!done) {
        kf_p1<<<dim3(3584), dim3(256), 0, stream>>>(ws, h2buf);
        kf_p2<<<dim3(3584), dim3(256), 0, stream>>>(g2, be2, W3, b3, ws, h2buf, out);
    }
}